// Round 10
// baseline (899.755 us; speedup 1.0000x reference)
//
#include <hip/hip_runtime.h>
#include <math.h>

#define HEADS   16
#define DHEAD   64
#define SEQ     2048
#define NB      2
#define DM      1024
#define NTOK    4096           // NB*SEQ
#define WEPS    1e-5

using f16x8   = __attribute__((ext_vector_type(8))) _Float16;
using f16x4   = __attribute__((ext_vector_type(4))) _Float16;
using fp16x2  = __attribute__((ext_vector_type(2))) __fp16;   // cvt_pkrtz result type
using floatx4 = __attribute__((ext_vector_type(4))) float;
using i32x4   = __attribute__((ext_vector_type(4))) int;

typedef __attribute__((address_space(1))) unsigned int gu32;
typedef __attribute__((address_space(3))) unsigned int lu32;

// lgkmcnt(0)-only barrier: does NOT drain vmcnt (register prefetch survives).
// Safe because LDS staging here is plain ds_write (not global_load_lds DMA).
#define BAR_LGKM()  asm volatile("s_waitcnt lgkmcnt(0)\n\ts_barrier" ::: "memory")
#define WAIT_LGKM() asm volatile("s_waitcnt lgkmcnt(0)" ::: "memory")

__device__ __forceinline__ unsigned short h16b(_Float16 h) {
    union { _Float16 h; unsigned short u; } c; c.h = h; return c.u;
}
__device__ __forceinline__ unsigned pk2u(fp16x2 v) {
    union { fp16x2 h; unsigned u; } c; c.h = v; return c.u;
}

// ---------------- weight |w| mean: pass 1 (partial sums in double) ----------------
__global__ void wsum1(const float* __restrict__ w0, const float* __restrict__ w1,
                      const float* __restrict__ w2, const float* __restrict__ w3,
                      double* __restrict__ partial) {
    const float* w = (blockIdx.y == 0) ? w0 : (blockIdx.y == 1) ? w1 : (blockIdx.y == 2) ? w2 : w3;
    int base = blockIdx.x * 16384;
    double s = 0.0;
    for (int i = threadIdx.x; i < 16384; i += 256)
        s += fabs((double)w[base + i]);
    __shared__ double sd[256];
    sd[threadIdx.x] = s;
    __syncthreads();
    for (int st = 128; st > 0; st >>= 1) {
        if (threadIdx.x < st) sd[threadIdx.x] += sd[threadIdx.x + st];
        __syncthreads();
    }
    if (threadIdx.x == 0) partial[blockIdx.y * 64 + blockIdx.x] = sd[0];
}

// ---------------- weight mean: pass 2 -> wscale[w] = clip(mean|w|, eps) ----------------
__global__ void wsum2(const double* __restrict__ partial, double* __restrict__ wscale) {
    int t = threadIdx.x;
    if (t < 4) {
        double s = 0.0;
        for (int i = 0; i < 64; i++) s += partial[t * 64 + i];
        double mean = s / (1024.0 * 1024.0);
        wscale[t] = (mean > WEPS) ? mean : WEPS;
    }
}

// ---------------- ternary weight quant -> int8 {-1,0,1} ----------------
__global__ void wquant(const float* __restrict__ w0, const float* __restrict__ w1,
                       const float* __restrict__ w2, const float* __restrict__ w3,
                       const double* __restrict__ wscale, signed char* __restrict__ wq) {
    int widx = blockIdx.y;
    const float* w = (widx == 0) ? w0 : (widx == 1) ? w1 : (widx == 2) ? w2 : w3;
    double ws = 1.0 / wscale[widx];
    int idx = (blockIdx.x * 256 + threadIdx.x) * 4;
    float4 wv = *(const float4*)(w + idx);
    char4 o;
    {
        double r = rint((double)wv.x * ws); r = r > 1.0 ? 1.0 : (r < -1.0 ? -1.0 : r); o.x = (signed char)r;
    } {
        double r = rint((double)wv.y * ws); r = r > 1.0 ? 1.0 : (r < -1.0 ? -1.0 : r); o.y = (signed char)r;
    } {
        double r = rint((double)wv.z * ws); r = r > 1.0 ? 1.0 : (r < -1.0 ? -1.0 : r); o.z = (signed char)r;
    } {
        double r = rint((double)wv.w * ws); r = r > 1.0 ? 1.0 : (r < -1.0 ? -1.0 : r); o.w = (signed char)r;
    }
    *(char4*)(wq + (size_t)widx * 1048576 + idx) = o;
}

// ---------------- per-token int8 absmax activation quant -> int8 ----------------
__device__ __forceinline__ void aquant_row(const float* __restrict__ row,
                                           signed char* __restrict__ dst_row,
                                           double* __restrict__ ascale_p) {
    int t = threadIdx.x;
    float4 xv = *(const float4*)(row + t * 4);
    float a = fmaxf(fmaxf(fabsf(xv.x), fabsf(xv.y)), fmaxf(fabsf(xv.z), fabsf(xv.w)));
    __shared__ float sm[256];
    sm[t] = a;
    __syncthreads();
    for (int st = 128; st > 0; st >>= 1) {
        if (t < st) sm[t] = fmaxf(sm[t], sm[t + st]);
        __syncthreads();
    }
    double mx = (double)sm[0];
    if (mx < WEPS) mx = WEPS;
    if (t == 0) *ascale_p = mx / 127.0;
    double xs = 127.0 / mx;
    char4 o;
    {
        double r = rint((double)xv.x * xs); r = r > 127.0 ? 127.0 : (r < -128.0 ? -128.0 : r); o.x = (signed char)r;
    } {
        double r = rint((double)xv.y * xs); r = r > 127.0 ? 127.0 : (r < -128.0 ? -128.0 : r); o.y = (signed char)r;
    } {
        double r = rint((double)xv.z * xs); r = r > 127.0 ? 127.0 : (r < -128.0 ? -128.0 : r); o.z = (signed char)r;
    } {
        double r = rint((double)xv.w * xs); r = r > 127.0 ? 127.0 : (r < -128.0 ? -128.0 : r); o.w = (signed char)r;
    }
    *(char4*)(dst_row + t * 4) = o;
}

__global__ void aquant(const float* __restrict__ src, signed char* __restrict__ dst,
                       double* __restrict__ ascale) {
    int tok = blockIdx.x;
    aquant_row(src + (size_t)tok * DM, dst + (size_t)tok * DM, ascale + tok);
}

// fused x + context quant: xq/cq and ascale_x/ascale_c are contiguous in ws
__global__ void aquant2(const float* __restrict__ x, const float* __restrict__ ctx,
                        signed char* __restrict__ dst, double* __restrict__ ascale) {
    int tok = blockIdx.x;
    const float* row = (tok < NTOK) ? x + (size_t)tok * DM : ctx + (size_t)(tok - NTOK) * DM;
    aquant_row(row, dst + (size_t)tok * DM, ascale + tok);
}

// ---------------- int8 MFMA GEMM core: C[m][n] = sum_k A[m][k]*W[n][k], exact i32 ----------
// m97 structure: async global_load_lds width-16 staging, 128x128 tile, BK=64.
// mode 0 (Q,K): separate hi/lo f16 limb planes at [b][h][t][dh] (lo at +4194304 elems)
// mode 2 (V):   separate limb planes, transposed+FRAGMENT-TILED [b][h][t/32][dh][t%32]
//               -> attn V-fragment f16x8 load is 1KB contiguous; ushort4 stores over t%32
// mode 1: plain fp32 [t][o].
__device__ __forceinline__ void gemm_core(
        const signed char* __restrict__ A, const signed char* __restrict__ W,
        const double* __restrict__ ascale, double wsc,
        void* __restrict__ outp, int mode, float prescale, int bx, int by) {
    __shared__ __align__(16) signed char lds_a[128 * 64];
    __shared__ __align__(16) signed char lds_b[128 * 64];
    const int tid  = threadIdx.x;
    const int wave = tid >> 6, lane = tid & 63;
    const int wr = wave >> 1, wc = wave & 1;
    const int quad = lane >> 4, l15 = lane & 15;
    const int row0 = by * 128, col0 = bx * 128;
    i32x4 acc[4][4] = {};

    const signed char* ga0 = A + (size_t)(row0 + (lane >> 2)) * DM + (lane & 3) * 16;
    const signed char* gb0 = W + (size_t)(col0 + (lane >> 2)) * DM + (lane & 3) * 16;

    for (int k0 = 0; k0 < DM; k0 += 64) {
        __syncthreads();
        #pragma unroll
        for (int t = 0; t < 2; t++) {
            const int i = wave + t * 4;                 // wave-uniform instr index, 8 total
            __builtin_amdgcn_global_load_lds(
                (const gu32*)(const void*)(ga0 + (size_t)i * 16 * DM + k0),
                (lu32*)(void*)(lds_a + i * 1024), 16, 0, 0);
            __builtin_amdgcn_global_load_lds(
                (const gu32*)(const void*)(gb0 + (size_t)i * 16 * DM + k0),
                (lu32*)(void*)(lds_b + i * 1024), 16, 0, 0);
        }
        __syncthreads();
        i32x4 af[4], bfr[4];
        #pragma unroll
        for (int mi = 0; mi < 4; mi++) {
            int r = wr * 64 + mi * 16 + l15;
            af[mi] = *(const i32x4*)&lds_a[r * 64 + quad * 16];
        }
        #pragma unroll
        for (int ni = 0; ni < 4; ni++) {
            int n = wc * 64 + ni * 16 + l15;
            bfr[ni] = *(const i32x4*)&lds_b[n * 64 + quad * 16];
        }
        #pragma unroll
        for (int mi = 0; mi < 4; mi++)
            #pragma unroll
            for (int ni = 0; ni < 4; ni++)
                acc[mi][ni] = __builtin_amdgcn_mfma_i32_16x16x64_i8(af[mi], bfr[ni], acc[mi][ni], 0, 0, 0);
    }

    #pragma unroll
    for (int mi = 0; mi < 4; mi++) {
        int tbase = row0 + wr * 64 + mi * 16 + quad * 4;
        if (mode == 2) {
            int bb = tbase >> 11, n = tbase & 2047;
            int tile = n >> 5, tin = n & 31;
            #pragma unroll
            for (int ni = 0; ni < 4; ni++) {
                int o = col0 + wc * 64 + ni * 16 + l15;
                int hh = o >> 6, dh = o & 63;
                ushort4 hv, lv;
                #pragma unroll
                for (int reg = 0; reg < 4; reg++) {
                    double sa = ascale[tbase + reg] * wsc;
                    float fv = (float)((double)acc[mi][ni][reg] * sa) * prescale;
                    _Float16 hl = (_Float16)fv;
                    _Float16 ml = (_Float16)((fv - (float)hl) * 2048.0f);
                    ((unsigned short*)&hv)[reg] = h16b(hl);
                    ((unsigned short*)&lv)[reg] = h16b(ml);
                }
                size_t idx = (((size_t)(bb * HEADS + hh) * 64 + tile) * 64 + dh) * 32 + tin;
                *(ushort4*)((unsigned short*)outp + idx)           = hv;
                *(ushort4*)((unsigned short*)outp + idx + 4194304) = lv;
            }
        } else {
            #pragma unroll
            for (int reg = 0; reg < 4; reg++) {
                int t = tbase + reg;
                double sa = ascale[t] * wsc;
                #pragma unroll
                for (int ni = 0; ni < 4; ni++) {
                    int o = col0 + wc * 64 + ni * 16 + l15;
                    float val = (float)((double)acc[mi][ni][reg] * sa);
                    if (mode == 1) {
                        ((float*)outp)[(size_t)t * DM + o] = val;
                    } else {
                        int bb = t >> 11, n = t & 2047, hh = o >> 6, dh = o & 63;
                        float fv = val * prescale;
                        _Float16 hl = (_Float16)fv;
                        _Float16 ml = (_Float16)((fv - (float)hl) * 2048.0f);
                        size_t idx = (((size_t)(bb * HEADS + hh) * SEQ + n) << 6) + dh;
                        ((unsigned short*)outp)[idx]           = h16b(hl);
                        ((unsigned short*)outp)[idx + 4194304] = h16b(ml);
                    }
                }
            }
        }
    }
}

// fused Q/K/V projections: 768 blocks = 3/CU co-resident (hides barrier drain)
// Q prescale folds softmax scale AND log2(e): 0.125 * 1.4426950408889634
__global__ __launch_bounds__(256) void gemm_qkv(
        const signed char* __restrict__ xq, const signed char* __restrict__ cq,
        const signed char* __restrict__ wqb, const double* __restrict__ ascale_x,
        const double* __restrict__ wscale, void* __restrict__ qkv) {
    const int which = blockIdx.x >> 3;          // 0=Q, 1=K, 2=V
    char* base = (char*)qkv + (size_t)which * 16777216;
    gemm_core(which == 0 ? xq : cq,
              wqb + (size_t)which * 1048576,
              ascale_x + (which ? NTOK : 0),
              wscale[which],
              base,
              which == 2 ? 2 : 0,
              which == 0 ? 0.18033688011112042f : 1.0f, blockIdx.x & 7, blockIdx.y);
}

__global__ __launch_bounds__(256) void gemm_o(
        const signed char* __restrict__ aq, const signed char* __restrict__ wo,
        const double* __restrict__ ascale, const double* __restrict__ wscale_p,
        float* __restrict__ out) {
    gemm_core(aq, wo, ascale, *wscale_p, out, 1, 1.0f, blockIdx.x, blockIdx.y);
}

// ---------------- MFMA flash attention v12: in-block KV split, 8 waves -------------------
// v11 post-mortem: MfmaUtil 40, VALU 38.6, occupancy 19% (2 waves/SIMD — grid-limited,
// VGPR=112 would allow 4). v12: 512-thread blocks; waves 0-3 process kv tiles [0,32),
// waves 4-7 tiles [32,64), SAME 128 q-rows. No running max in this softmax -> partials
// merge by plain addition (O = O0+O1, l = l0+l1) through LDS at block end (overlays the
// P buffers, 2 extra syncthreads). 4 waves/SIMD, per-wave schedule unchanged (v10 diet:
// exp2 builtin, cvt_pkrtz limbs, zero-quad init, setprio; V frags in regs from
// fragment-tiled global, prefetched one full tile ahead; K via LDS, per-half buffer).
#define KH_IDX(row, d8) (((row) * 8 + ((d8) ^ ((row) & 7))) * 8)       // halves

__global__ __launch_bounds__(512, 4) void attn_mfma(
        const unsigned short* __restrict__ qhg, const unsigned short* __restrict__ qlg,
        const unsigned short* __restrict__ khg, const unsigned short* __restrict__ klg,
        const unsigned short* __restrict__ vhg, const unsigned short* __restrict__ vlg,
        float* __restrict__ out) {
    // smem layout (57344 B): KhL[2][2048]h | KlL[2][2048]h | PhL[8][1152]h | PlL[8][1152]h
    //                        | Lp[8][2][16][4]f ; merge buffer Om (32KB f32) overlays PhL+
    __shared__ __align__(16) char smem[57344];
    _Float16* KhL = (_Float16*)smem;                     // +0     (8 KB, half-indexed)
    _Float16* KlL = (_Float16*)(smem + 8192);            // +8192  (8 KB)
    _Float16* PhL = (_Float16*)(smem + 16384);           // +16384 (18 KB, per wave 1152)
    _Float16* PlL = (_Float16*)(smem + 34816);           // +34816 (18 KB)
    float*    Lpf = (float*)(smem + 53248);              // +53248 (4 KB)
    float*    Om  = (float*)(smem + 16384);              // merge overlay (32 KB <= 36 KB)

    const int lin  = blockIdx.x;
    const int bh   = (lin & 7) * 4 + ((lin >> 3) & 3);   // co-resident blocks share bh
    const int qblk = (lin >> 5) & 15;                    // 16 q-blocks of 128 rows
    const int tid  = threadIdx.x;
    const int wave = tid >> 6, lane = tid & 63;
    const int whalf = wave >> 2, wsub = wave & 3;        // kv-half, q-sub-block
    const int l15  = lane & 15, quad = lane >> 4;
    const int qbase = qblk * 128 + wsub * 32;

    // ---- Q fragments: direct f16x8 loads from separate limb planes ----
    f16x8 qh[2][2], qm[2][2];
    #pragma unroll
    for (int qs = 0; qs < 2; qs++) {
        #pragma unroll
        for (int c = 0; c < 2; c++) {
            size_t off = (((size_t)bh * SEQ + qbase + qs * 16 + l15) << 6) + c * 32 + quad * 8;
            qh[qs][c] = *(const f16x8*)(qhg + off);
            qm[qs][c] = *(const f16x8*)(qlg + off);
        }
    }

    floatx4 och[2][4] = {};   // [qs][nh] hi-scale PV acc
    floatx4 ocm[2][4] = {};   // [qs][nh] 2^-11-scale PV acc
    float lsum[2] = {0.f, 0.f};
    const floatx4 zf = {};    // shared zero quad for QK acc init

    const unsigned short* khb = khg + ((size_t)bh * SEQ << 6);   // [t][dh] plane
    const unsigned short* klb = klg + ((size_t)bh * SEQ << 6);
    const unsigned short* vhb = vhg + ((size_t)bh << 17);        // fragment-tiled plane
    const unsigned short* vlb = vlg + ((size_t)bh << 17);

    const int kk = (tid >> 3) & 31, d8 = tid & 7;        // K staging row/chunk (per half)
    const int kvbase = whalf * 1024;                     // this half's kv row offset
    _Float16* KhH = KhL + whalf * 2048;
    _Float16* KlH = KlL + whalf * 2048;

    // prologue: prefetch K tile 0 (of this half) into regs; V tile 0 fragments into regs
    uint4 kh_pf = *(const uint4*)(khb + ((size_t)(kvbase + kk) << 6) + d8 * 8);
    uint4 kl_pf = *(const uint4*)(klb + ((size_t)(kvbase + kk) << 6) + d8 * 8);
    f16x8 vfh[4], vfm[4];
    #pragma unroll
    for (int nh = 0; nh < 4; nh++) {
        size_t vo = ((size_t)((whalf * 32) * 64 + nh * 16 + l15) << 5) + quad * 8;
        vfh[nh] = *(const f16x8*)(vhb + vo);
        vfm[nh] = *(const f16x8*)(vlb + vo);
    }

    for (int t = 0; t < 32; t++) {
        BAR_LGKM();   // LDS reads from previous tile done (no vmcnt drain)

        *(uint4*)&KhH[KH_IDX(kk, d8)] = kh_pf;   // auto vmcnt wait on K prefetch regs only
        *(uint4*)&KlH[KH_IDX(kk, d8)] = kl_pf;

        if (t + 1 < 32) {   // prefetch K(t+1): full tile of latency tolerance
            kh_pf = *(const uint4*)(khb + ((size_t)(kvbase + (t + 1) * 32 + kk) << 6) + d8 * 8);
            kl_pf = *(const uint4*)(klb + ((size_t)(kvbase + (t + 1) * 32 + kk) << 6) + d8 * 8);
        }

        BAR_LGKM();   // staged K visible

        // K fragments (A-operand), direct f16x8 from this half's LDS buffer
        f16x8 kfh[2][2], kfl[2][2];
        #pragma unroll
        for (int ms = 0; ms < 2; ms++) {
            #pragma unroll
            for (int c = 0; c < 2; c++) {
                kfh[ms][c] = *(const f16x8*)&KhH[KH_IDX(ms * 16 + l15, c * 4 + quad)];
                kfl[ms][c] = *(const f16x8*)&KlH[KH_IDX(ms * 16 + l15, c * 4 + quad)];
            }
        }

        // QK MFMAs (24): 2 qs x 2 ms x 6
        __builtin_amdgcn_s_setprio(1);
        floatx4 ah[2][2], am[2][2];
        #pragma unroll
        for (int qs = 0; qs < 2; qs++) {
            #pragma unroll
            for (int ms = 0; ms < 2; ms++) {
                ah[qs][ms] = __builtin_amdgcn_mfma_f32_16x16x32_f16(kfh[ms][0], qh[qs][0], zf, 0, 0, 0);
                am[qs][ms] = __builtin_amdgcn_mfma_f32_16x16x32_f16(kfh[ms][0], qm[qs][0], zf, 0, 0, 0);
                am[qs][ms] = __builtin_amdgcn_mfma_f32_16x16x32_f16(kfl[ms][0], qh[qs][0], am[qs][ms], 0, 0, 0);
                ah[qs][ms] = __builtin_amdgcn_mfma_f32_16x16x32_f16(kfh[ms][1], qh[qs][1], ah[qs][ms], 0, 0, 0);
                am[qs][ms] = __builtin_amdgcn_mfma_f32_16x16x32_f16(kfh[ms][1], qm[qs][1], am[qs][ms], 0, 0, 0);
                am[qs][ms] = __builtin_amdgcn_mfma_f32_16x16x32_f16(kfl[ms][1], qh[qs][1], am[qs][ms], 0, 0, 0);
            }
        }
        __builtin_amdgcn_s_setprio(0);

        // softmax: p = exp2(s) -> P limb planes (cvt_pkrtz packed)
        #pragma unroll
        for (int qs = 0; qs < 2; qs++) {
            #pragma unroll
            for (int ms = 0; ms < 2; ms++) {
                float p0 = __builtin_amdgcn_exp2f(ah[qs][ms][0] + am[qs][ms][0] * 4.8828125e-4f);
                float p1 = __builtin_amdgcn_exp2f(ah[qs][ms][1] + am[qs][ms][1] * 4.8828125e-4f);
                float p2 = __builtin_amdgcn_exp2f(ah[qs][ms][2] + am[qs][ms][2] * 4.8828125e-4f);
                float p3 = __builtin_amdgcn_exp2f(ah[qs][ms][3] + am[qs][ms][3] * 4.8828125e-4f);
                lsum[qs] += (p0 + p1) + (p2 + p3);
                fp16x2 h01 = __builtin_amdgcn_cvt_pkrtz(p0, p1);
                fp16x2 h23 = __builtin_amdgcn_cvt_pkrtz(p2, p3);
                fp16x2 m01 = __builtin_amdgcn_cvt_pkrtz((p0 - (float)h01[0]) * 2048.0f,
                                                        (p1 - (float)h01[1]) * 2048.0f);
                fp16x2 m23 = __builtin_amdgcn_cvt_pkrtz((p2 - (float)h23[0]) * 2048.0f,
                                                        (p3 - (float)h23[1]) * 2048.0f);
                int poff = wave * 1152 + (qs * 16 + l15) * 36 + ms * 16 + quad * 4;
                *(uint2*)&PhL[poff] = make_uint2(pk2u(h01), pk2u(h23));
                *(uint2*)&PlL[poff] = make_uint2(pk2u(m01), pk2u(m23));
            }
        }
        WAIT_LGKM();   // P writes visible to own wave's cross-lane reads (vmcnt untouched)

        // PV MFMAs (24): V fragments already in regs (prefetched last iteration)
        __builtin_amdgcn_s_setprio(1);
        #pragma unroll
        for (int qs = 0; qs < 2; qs++) {
            f16x8 pfh = *(const f16x8*)&PhL[wave * 1152 + (qs * 16 + l15) * 36 + quad * 8];
            f16x8 pfm = *(const f16x8*)&PlL[wave * 1152 + (qs * 16 + l15) * 36 + quad * 8];
            #pragma unroll
            for (int nh = 0; nh < 4; nh++) {
                och[qs][nh] = __builtin_amdgcn_mfma_f32_16x16x32_f16(pfh, vfh[nh], och[qs][nh], 0, 0, 0);
                ocm[qs][nh] = __builtin_amdgcn_mfma_f32_16x16x32_f16(pfh, vfm[nh], ocm[qs][nh], 0, 0, 0);
                ocm[qs][nh] = __builtin_amdgcn_mfma_f32_16x16x32_f16(pfm, vfh[nh], ocm[qs][nh], 0, 0, 0);
            }
        }
        __builtin_amdgcn_s_setprio(0);

        // prefetch V(t+1) fragments from fragment-tiled global (1KB contiguous/instr);
        // consumed at PV(t+1): slack = barrier + K stage + QK + softmax (>>L2 latency)
        if (t + 1 < 32) {
            #pragma unroll
            for (int nh = 0; nh < 4; nh++) {
                size_t vo = ((size_t)((whalf * 32 + t + 1) * 64 + nh * 16 + l15) << 5) + quad * 8;
                vfh[nh] = *(const f16x8*)(vhb + vo);
                vfm[nh] = *(const f16x8*)(vlb + vo);
            }
        }
    }

    // ---- epilogue: merge halves (plain adds — no max tracking), normalize, write ----
    Lpf[((wave * 2 + 0) * 16 + l15) * 4 + quad] = lsum[0];
    Lpf[((wave * 2 + 1) * 16 + l15) * 4 + quad] = lsum[1];
    __syncthreads();   // all PV/P-reads done + Lp visible (Om overlays P buffers)

    if (whalf == 1) {  // half1 deposits partial O into merge buffer
        #pragma unroll
        for (int qs = 0; qs < 2; qs++)
            #pragma unroll
            for (int nh = 0; nh < 4; nh++)
                #pragma unroll
                for (int r = 0; r < 4; r++)
                    Om[((((wsub * 2 + qs) * 4 + nh) * 4 + r) << 6) + lane] =
                        och[qs][nh][r] + ocm[qs][nh][r] * 4.8828125e-4f;
    }
    __syncthreads();

    if (whalf == 0) {
        int b = bh >> 4, h = bh & 15;
        #pragma unroll
        for (int qs = 0; qs < 2; qs++) {
            float linv[4];
            #pragma unroll
            for (int r = 0; r < 4; r++) {
                float4 a = *(const float4*)&Lpf[((wave * 2 + qs) * 16 + quad * 4 + r) * 4];
                float4 c = *(const float4*)&Lpf[(((wave + 4) * 2 + qs) * 16 + quad * 4 + r) * 4];
                linv[r] = 1.0f / (a.x + a.y + a.z + a.w + c.x + c.y + c.z + c.w);
            }
            #pragma unroll
            for (int nh = 0; nh < 4; nh++) {
                #pragma unroll
                for (int r = 0; r < 4; r++) {
                    int token = b * SEQ + qbase + qs * 16 + quad * 4 + r;
                    float val = (och[qs][nh][r] + ocm[qs][nh][r] * 4.8828125e-4f
                                 + Om[((((wsub * 2 + qs) * 4 + nh) * 4 + r) << 6) + lane]) * linv[r];
                    out[(size_t)token * DM + h * 64 + nh * 16 + l15] = val;
                }
            }
        }
    }
}

extern "C" void kernel_launch(void* const* d_in, const int* in_sizes, int n_in,
                              void* d_out, int out_size, void* d_ws, size_t ws_size,
                              hipStream_t stream) {
    const float* x       = (const float*)d_in[0];
    const float* context = (const float*)d_in[1];
    const float* Wq      = (const float*)d_in[2];
    const float* Wk      = (const float*)d_in[3];
    const float* Wv      = (const float*)d_in[4];
    const float* Wo      = (const float*)d_in[5];
    char* ws = (char*)d_ws;

    // workspace layout (~71.4 MB). Plane region at +21102592:
    //   Qh 8MB | Ql 8MB | Kh 8MB | Kl 8MB | Vh 8MB | Vl 8MB  (48 MB total)
    double* wscale   = (double*)(ws + 0);            // 4 doubles
    double* partial  = (double*)(ws + 4096);         // 256 doubles
    double* ascale_x = (double*)(ws + 8192);         // 8192 doubles (x then ctx)
    double* ascale_a = (double*)(ws + 73728);        // 4096 doubles
    signed char* wqb = (signed char*)(ws + 131072);          // 4 x 1 MB int8
    signed char* xq  = (signed char*)(ws + 4325376);         // 4 MB (cq follows)
    signed char* cq  = (signed char*)(ws + 8519680);         // 4 MB
    float* attn_out  = (float*)(ws + 4325376);               // aliases xq+cq region (16 MB)
    char* planes     = ws + 21102592;                        // 48 MB limb planes
    signed char* aq  = (signed char*)(ws + 21102592);        // aliases Q planes, used after attention

    unsigned short* qhg = (unsigned short*)planes;
    unsigned short* qlg = qhg + 4194304;
    unsigned short* khg = (unsigned short*)(planes + 16777216);
    unsigned short* klg = khg + 4194304;
    unsigned short* vhg = (unsigned short*)(planes + 33554432);
    unsigned short* vlg = vhg + 4194304;

    wsum1<<<dim3(64, 4), 256, 0, stream>>>(Wq, Wk, Wv, Wo, partial);
    wsum2<<<1, 64, 0, stream>>>(partial, wscale);
    wquant<<<dim3(1024, 4), 256, 0, stream>>>(Wq, Wk, Wv, Wo, wscale, wqb);
    aquant2<<<2 * NTOK, 256, 0, stream>>>(x, context, xq, ascale_x);

    gemm_qkv<<<dim3(24, 32), 256, 0, stream>>>(xq, cq, wqb, ascale_x, wscale, planes);

    attn_mfma<<<dim3(512), 512, 0, stream>>>(qhg, qlg, khg, klg, vhg, vlg, attn_out);

    aquant<<<NTOK, 256, 0, stream>>>(attn_out, aq, ascale_a);
    gemm_o<<<dim3(8, 32), 256, 0, stream>>>(aq, wqb + 3145728, ascale_a, wscale + 3, (float*)d_out);
}

// Round 11
// 294.602 us; speedup vs baseline: 3.0541x; 3.0541x over previous
//
#include <hip/hip_runtime.h>
#include <math.h>

#define HEADS   16
#define DHEAD   64
#define SEQ     2048
#define NB      2
#define DM      1024
#define NTOK    4096           // NB*SEQ
#define WEPS    1e-5

using f16x8   = __attribute__((ext_vector_type(8))) _Float16;
using f16x4   = __attribute__((ext_vector_type(4))) _Float16;
using fp16x2  = __attribute__((ext_vector_type(2))) __fp16;   // cvt_pkrtz result type
using floatx4 = __attribute__((ext_vector_type(4))) float;
using i32x4   = __attribute__((ext_vector_type(4))) int;

typedef __attribute__((address_space(1))) unsigned int gu32;
typedef __attribute__((address_space(3))) unsigned int lu32;

// lgkmcnt(0)-only barrier: does NOT drain vmcnt (register prefetch survives).
// Safe because LDS staging here is plain ds_write (not global_load_lds DMA).
#define BAR_LGKM()  asm volatile("s_waitcnt lgkmcnt(0)\n\ts_barrier" ::: "memory")
#define WAIT_LGKM() asm volatile("s_waitcnt lgkmcnt(0)" ::: "memory")

__device__ __forceinline__ unsigned short h16b(_Float16 h) {
    union { _Float16 h; unsigned short u; } c; c.h = h; return c.u;
}
__device__ __forceinline__ unsigned pk2u(fp16x2 v) {
    union { fp16x2 h; unsigned u; } c; c.h = v; return c.u;
}

// ---------------- weight |w| mean: pass 1 (partial sums in double) ----------------
__global__ void wsum1(const float* __restrict__ w0, const float* __restrict__ w1,
                      const float* __restrict__ w2, const float* __restrict__ w3,
                      double* __restrict__ partial) {
    const float* w = (blockIdx.y == 0) ? w0 : (blockIdx.y == 1) ? w1 : (blockIdx.y == 2) ? w2 : w3;
    int base = blockIdx.x * 16384;
    double s = 0.0;
    for (int i = threadIdx.x; i < 16384; i += 256)
        s += fabs((double)w[base + i]);
    __shared__ double sd[256];
    sd[threadIdx.x] = s;
    __syncthreads();
    for (int st = 128; st > 0; st >>= 1) {
        if (threadIdx.x < st) sd[threadIdx.x] += sd[threadIdx.x + st];
        __syncthreads();
    }
    if (threadIdx.x == 0) partial[blockIdx.y * 64 + blockIdx.x] = sd[0];
}

// ---------------- weight mean: pass 2 -> wscale[w] = clip(mean|w|, eps) ----------------
__global__ void wsum2(const double* __restrict__ partial, double* __restrict__ wscale) {
    int t = threadIdx.x;
    if (t < 4) {
        double s = 0.0;
        for (int i = 0; i < 64; i++) s += partial[t * 64 + i];
        double mean = s / (1024.0 * 1024.0);
        wscale[t] = (mean > WEPS) ? mean : WEPS;
    }
}

// ---------------- ternary weight quant -> int8 {-1,0,1} ----------------
__global__ void wquant(const float* __restrict__ w0, const float* __restrict__ w1,
                       const float* __restrict__ w2, const float* __restrict__ w3,
                       const double* __restrict__ wscale, signed char* __restrict__ wq) {
    int widx = blockIdx.y;
    const float* w = (widx == 0) ? w0 : (widx == 1) ? w1 : (widx == 2) ? w2 : w3;
    double ws = 1.0 / wscale[widx];
    int idx = (blockIdx.x * 256 + threadIdx.x) * 4;
    float4 wv = *(const float4*)(w + idx);
    char4 o;
    {
        double r = rint((double)wv.x * ws); r = r > 1.0 ? 1.0 : (r < -1.0 ? -1.0 : r); o.x = (signed char)r;
    } {
        double r = rint((double)wv.y * ws); r = r > 1.0 ? 1.0 : (r < -1.0 ? -1.0 : r); o.y = (signed char)r;
    } {
        double r = rint((double)wv.z * ws); r = r > 1.0 ? 1.0 : (r < -1.0 ? -1.0 : r); o.z = (signed char)r;
    } {
        double r = rint((double)wv.w * ws); r = r > 1.0 ? 1.0 : (r < -1.0 ? -1.0 : r); o.w = (signed char)r;
    }
    *(char4*)(wq + (size_t)widx * 1048576 + idx) = o;
}

// ---------------- per-token int8 absmax activation quant -> int8 ----------------
__device__ __forceinline__ void aquant_row(const float* __restrict__ row,
                                           signed char* __restrict__ dst_row,
                                           double* __restrict__ ascale_p) {
    int t = threadIdx.x;
    float4 xv = *(const float4*)(row + t * 4);
    float a = fmaxf(fmaxf(fabsf(xv.x), fabsf(xv.y)), fmaxf(fabsf(xv.z), fabsf(xv.w)));
    __shared__ float sm[256];
    sm[t] = a;
    __syncthreads();
    for (int st = 128; st > 0; st >>= 1) {
        if (t < st) sm[t] = fmaxf(sm[t], sm[t + st]);
        __syncthreads();
    }
    double mx = (double)sm[0];
    if (mx < WEPS) mx = WEPS;
    if (t == 0) *ascale_p = mx / 127.0;
    double xs = 127.0 / mx;
    char4 o;
    {
        double r = rint((double)xv.x * xs); r = r > 127.0 ? 127.0 : (r < -128.0 ? -128.0 : r); o.x = (signed char)r;
    } {
        double r = rint((double)xv.y * xs); r = r > 127.0 ? 127.0 : (r < -128.0 ? -128.0 : r); o.y = (signed char)r;
    } {
        double r = rint((double)xv.z * xs); r = r > 127.0 ? 127.0 : (r < -128.0 ? -128.0 : r); o.z = (signed char)r;
    } {
        double r = rint((double)xv.w * xs); r = r > 127.0 ? 127.0 : (r < -128.0 ? -128.0 : r); o.w = (signed char)r;
    }
    *(char4*)(dst_row + t * 4) = o;
}

__global__ void aquant(const float* __restrict__ src, signed char* __restrict__ dst,
                       double* __restrict__ ascale) {
    int tok = blockIdx.x;
    aquant_row(src + (size_t)tok * DM, dst + (size_t)tok * DM, ascale + tok);
}

// fused x + context quant: xq/cq and ascale_x/ascale_c are contiguous in ws
__global__ void aquant2(const float* __restrict__ x, const float* __restrict__ ctx,
                        signed char* __restrict__ dst, double* __restrict__ ascale) {
    int tok = blockIdx.x;
    const float* row = (tok < NTOK) ? x + (size_t)tok * DM : ctx + (size_t)(tok - NTOK) * DM;
    aquant_row(row, dst + (size_t)tok * DM, ascale + tok);
}

// ---------------- int8 MFMA GEMM core: C[m][n] = sum_k A[m][k]*W[n][k], exact i32 ----------
// m97 structure: async global_load_lds width-16 staging, 128x128 tile, BK=64.
// mode 0 (Q,K): separate hi/lo f16 limb planes at [b][h][t][dh] (lo at +4194304 elems)
// mode 2 (V):   separate limb planes, transposed+FRAGMENT-TILED [b][h][t/32][dh][t%32]
//               -> attn V-fragment f16x8 load is 1KB contiguous; ushort4 stores over t%32
// mode 1: plain fp32 [t][o].
__device__ __forceinline__ void gemm_core(
        const signed char* __restrict__ A, const signed char* __restrict__ W,
        const double* __restrict__ ascale, double wsc,
        void* __restrict__ outp, int mode, float prescale, int bx, int by) {
    __shared__ __align__(16) signed char lds_a[128 * 64];
    __shared__ __align__(16) signed char lds_b[128 * 64];
    const int tid  = threadIdx.x;
    const int wave = tid >> 6, lane = tid & 63;
    const int wr = wave >> 1, wc = wave & 1;
    const int quad = lane >> 4, l15 = lane & 15;
    const int row0 = by * 128, col0 = bx * 128;
    i32x4 acc[4][4] = {};

    const signed char* ga0 = A + (size_t)(row0 + (lane >> 2)) * DM + (lane & 3) * 16;
    const signed char* gb0 = W + (size_t)(col0 + (lane >> 2)) * DM + (lane & 3) * 16;

    for (int k0 = 0; k0 < DM; k0 += 64) {
        __syncthreads();
        #pragma unroll
        for (int t = 0; t < 2; t++) {
            const int i = wave + t * 4;                 // wave-uniform instr index, 8 total
            __builtin_amdgcn_global_load_lds(
                (const gu32*)(const void*)(ga0 + (size_t)i * 16 * DM + k0),
                (lu32*)(void*)(lds_a + i * 1024), 16, 0, 0);
            __builtin_amdgcn_global_load_lds(
                (const gu32*)(const void*)(gb0 + (size_t)i * 16 * DM + k0),
                (lu32*)(void*)(lds_b + i * 1024), 16, 0, 0);
        }
        __syncthreads();
        i32x4 af[4], bfr[4];
        #pragma unroll
        for (int mi = 0; mi < 4; mi++) {
            int r = wr * 64 + mi * 16 + l15;
            af[mi] = *(const i32x4*)&lds_a[r * 64 + quad * 16];
        }
        #pragma unroll
        for (int ni = 0; ni < 4; ni++) {
            int n = wc * 64 + ni * 16 + l15;
            bfr[ni] = *(const i32x4*)&lds_b[n * 64 + quad * 16];
        }
        #pragma unroll
        for (int mi = 0; mi < 4; mi++)
            #pragma unroll
            for (int ni = 0; ni < 4; ni++)
                acc[mi][ni] = __builtin_amdgcn_mfma_i32_16x16x64_i8(af[mi], bfr[ni], acc[mi][ni], 0, 0, 0);
    }

    #pragma unroll
    for (int mi = 0; mi < 4; mi++) {
        int tbase = row0 + wr * 64 + mi * 16 + quad * 4;
        if (mode == 2) {
            int bb = tbase >> 11, n = tbase & 2047;
            int tile = n >> 5, tin = n & 31;
            #pragma unroll
            for (int ni = 0; ni < 4; ni++) {
                int o = col0 + wc * 64 + ni * 16 + l15;
                int hh = o >> 6, dh = o & 63;
                ushort4 hv, lv;
                #pragma unroll
                for (int reg = 0; reg < 4; reg++) {
                    double sa = ascale[tbase + reg] * wsc;
                    float fv = (float)((double)acc[mi][ni][reg] * sa) * prescale;
                    _Float16 hl = (_Float16)fv;
                    _Float16 ml = (_Float16)((fv - (float)hl) * 2048.0f);
                    ((unsigned short*)&hv)[reg] = h16b(hl);
                    ((unsigned short*)&lv)[reg] = h16b(ml);
                }
                size_t idx = (((size_t)(bb * HEADS + hh) * 64 + tile) * 64 + dh) * 32 + tin;
                *(ushort4*)((unsigned short*)outp + idx)           = hv;
                *(ushort4*)((unsigned short*)outp + idx + 4194304) = lv;
            }
        } else {
            #pragma unroll
            for (int reg = 0; reg < 4; reg++) {
                int t = tbase + reg;
                double sa = ascale[t] * wsc;
                #pragma unroll
                for (int ni = 0; ni < 4; ni++) {
                    int o = col0 + wc * 64 + ni * 16 + l15;
                    float val = (float)((double)acc[mi][ni][reg] * sa);
                    if (mode == 1) {
                        ((float*)outp)[(size_t)t * DM + o] = val;
                    } else {
                        int bb = t >> 11, n = t & 2047, hh = o >> 6, dh = o & 63;
                        float fv = val * prescale;
                        _Float16 hl = (_Float16)fv;
                        _Float16 ml = (_Float16)((fv - (float)hl) * 2048.0f);
                        size_t idx = (((size_t)(bb * HEADS + hh) * SEQ + n) << 6) + dh;
                        ((unsigned short*)outp)[idx]           = h16b(hl);
                        ((unsigned short*)outp)[idx + 4194304] = h16b(ml);
                    }
                }
            }
        }
    }
}

// fused Q/K/V projections: 768 blocks = 3/CU co-resident (hides barrier drain)
// Q prescale folds softmax scale AND log2(e): 0.125 * 1.4426950408889634
__global__ __launch_bounds__(256) void gemm_qkv(
        const signed char* __restrict__ xq, const signed char* __restrict__ cq,
        const signed char* __restrict__ wqb, const double* __restrict__ ascale_x,
        const double* __restrict__ wscale, void* __restrict__ qkv) {
    const int which = blockIdx.x >> 3;          // 0=Q, 1=K, 2=V
    char* base = (char*)qkv + (size_t)which * 16777216;
    gemm_core(which == 0 ? xq : cq,
              wqb + (size_t)which * 1048576,
              ascale_x + (which ? NTOK : 0),
              wscale[which],
              base,
              which == 2 ? 2 : 0,
              which == 0 ? 0.18033688011112042f : 1.0f, blockIdx.x & 7, blockIdx.y);
}

__global__ __launch_bounds__(256) void gemm_o(
        const signed char* __restrict__ aq, const signed char* __restrict__ wo,
        const double* __restrict__ ascale, const double* __restrict__ wscale_p,
        float* __restrict__ out) {
    gemm_core(aq, wo, ascale, *wscale_p, out, 1, 1.0f, blockIdx.x, blockIdx.y);
}

// ---------------- MFMA flash attention v13: v12 KV-split with fixed launch bounds ---------
// v12 post-mortem: __launch_bounds__(512,4) on this hipcc follows CUDA min-BLOCKS-per-CU
// semantics -> 4 blocks x 8 waves = 8 waves/SIMD -> 64-VGPR cap -> full accumulator spill
// (FETCH 1.7GB, HBM 56%, MfmaUtil 5.7). Fix: (512,2) -> 2 blocks/CU = 4 waves/SIMD ->
// 128-VGPR cap >= the ~112 this kernel needs. Structure unchanged from v12:
// waves 0-3 kv tiles [0,32), waves 4-7 tiles [32,64), same 128 q-rows; partials merge by
// plain addition through LDS overlay (no running max in this softmax). v10 diet + V frags
// in regs from fragment-tiled global (1 tile ahead), K via per-half LDS buffers.
#define KH_IDX(row, d8) (((row) * 8 + ((d8) ^ ((row) & 7))) * 8)       // halves

__global__ __launch_bounds__(512, 2) void attn_mfma(
        const unsigned short* __restrict__ qhg, const unsigned short* __restrict__ qlg,
        const unsigned short* __restrict__ khg, const unsigned short* __restrict__ klg,
        const unsigned short* __restrict__ vhg, const unsigned short* __restrict__ vlg,
        float* __restrict__ out) {
    // smem layout (57344 B): KhL[2][2048]h | KlL[2][2048]h | PhL[8][1152]h | PlL[8][1152]h
    //                        | Lp[8][2][16][4]f ; merge buffer Om (32KB f32) overlays PhL+
    __shared__ __align__(16) char smem[57344];
    _Float16* KhL = (_Float16*)smem;                     // +0     (8 KB, half-indexed)
    _Float16* KlL = (_Float16*)(smem + 8192);            // +8192  (8 KB)
    _Float16* PhL = (_Float16*)(smem + 16384);           // +16384 (18 KB, per wave 1152)
    _Float16* PlL = (_Float16*)(smem + 34816);           // +34816 (18 KB)
    float*    Lpf = (float*)(smem + 53248);              // +53248 (4 KB)
    float*    Om  = (float*)(smem + 16384);              // merge overlay (32 KB <= 36 KB)

    const int lin  = blockIdx.x;
    const int bh   = (lin & 7) * 4 + ((lin >> 3) & 3);   // co-resident blocks share bh
    const int qblk = (lin >> 5) & 15;                    // 16 q-blocks of 128 rows
    const int tid  = threadIdx.x;
    const int wave = tid >> 6, lane = tid & 63;
    const int whalf = wave >> 2, wsub = wave & 3;        // kv-half, q-sub-block
    const int l15  = lane & 15, quad = lane >> 4;
    const int qbase = qblk * 128 + wsub * 32;

    // ---- Q fragments: direct f16x8 loads from separate limb planes ----
    f16x8 qh[2][2], qm[2][2];
    #pragma unroll
    for (int qs = 0; qs < 2; qs++) {
        #pragma unroll
        for (int c = 0; c < 2; c++) {
            size_t off = (((size_t)bh * SEQ + qbase + qs * 16 + l15) << 6) + c * 32 + quad * 8;
            qh[qs][c] = *(const f16x8*)(qhg + off);
            qm[qs][c] = *(const f16x8*)(qlg + off);
        }
    }

    floatx4 och[2][4] = {};   // [qs][nh] hi-scale PV acc
    floatx4 ocm[2][4] = {};   // [qs][nh] 2^-11-scale PV acc
    float lsum[2] = {0.f, 0.f};
    const floatx4 zf = {};    // shared zero quad for QK acc init

    const unsigned short* khb = khg + ((size_t)bh * SEQ << 6);   // [t][dh] plane
    const unsigned short* klb = klg + ((size_t)bh * SEQ << 6);
    const unsigned short* vhb = vhg + ((size_t)bh << 17);        // fragment-tiled plane
    const unsigned short* vlb = vlg + ((size_t)bh << 17);

    const int kk = (tid >> 3) & 31, d8 = tid & 7;        // K staging row/chunk (per half)
    const int kvbase = whalf * 1024;                     // this half's kv row offset
    _Float16* KhH = KhL + whalf * 2048;
    _Float16* KlH = KlL + whalf * 2048;

    // prologue: prefetch K tile 0 (of this half) into regs; V tile 0 fragments into regs
    uint4 kh_pf = *(const uint4*)(khb + ((size_t)(kvbase + kk) << 6) + d8 * 8);
    uint4 kl_pf = *(const uint4*)(klb + ((size_t)(kvbase + kk) << 6) + d8 * 8);
    f16x8 vfh[4], vfm[4];
    #pragma unroll
    for (int nh = 0; nh < 4; nh++) {
        size_t vo = ((size_t)((whalf * 32) * 64 + nh * 16 + l15) << 5) + quad * 8;
        vfh[nh] = *(const f16x8*)(vhb + vo);
        vfm[nh] = *(const f16x8*)(vlb + vo);
    }

    for (int t = 0; t < 32; t++) {
        BAR_LGKM();   // LDS reads from previous tile done (no vmcnt drain)

        *(uint4*)&KhH[KH_IDX(kk, d8)] = kh_pf;   // auto vmcnt wait on K prefetch regs only
        *(uint4*)&KlH[KH_IDX(kk, d8)] = kl_pf;

        if (t + 1 < 32) {   // prefetch K(t+1): full tile of latency tolerance
            kh_pf = *(const uint4*)(khb + ((size_t)(kvbase + (t + 1) * 32 + kk) << 6) + d8 * 8);
            kl_pf = *(const uint4*)(klb + ((size_t)(kvbase + (t + 1) * 32 + kk) << 6) + d8 * 8);
        }

        BAR_LGKM();   // staged K visible

        // K fragments (A-operand), direct f16x8 from this half's LDS buffer
        f16x8 kfh[2][2], kfl[2][2];
        #pragma unroll
        for (int ms = 0; ms < 2; ms++) {
            #pragma unroll
            for (int c = 0; c < 2; c++) {
                kfh[ms][c] = *(const f16x8*)&KhH[KH_IDX(ms * 16 + l15, c * 4 + quad)];
                kfl[ms][c] = *(const f16x8*)&KlH[KH_IDX(ms * 16 + l15, c * 4 + quad)];
            }
        }

        // QK MFMAs (24): 2 qs x 2 ms x 6
        __builtin_amdgcn_s_setprio(1);
        floatx4 ah[2][2], am[2][2];
        #pragma unroll
        for (int qs = 0; qs < 2; qs++) {
            #pragma unroll
            for (int ms = 0; ms < 2; ms++) {
                ah[qs][ms] = __builtin_amdgcn_mfma_f32_16x16x32_f16(kfh[ms][0], qh[qs][0], zf, 0, 0, 0);
                am[qs][ms] = __builtin_amdgcn_mfma_f32_16x16x32_f16(kfh[ms][0], qm[qs][0], zf, 0, 0, 0);
                am[qs][ms] = __builtin_amdgcn_mfma_f32_16x16x32_f16(kfl[ms][0], qh[qs][0], am[qs][ms], 0, 0, 0);
                ah[qs][ms] = __builtin_amdgcn_mfma_f32_16x16x32_f16(kfh[ms][1], qh[qs][1], ah[qs][ms], 0, 0, 0);
                am[qs][ms] = __builtin_amdgcn_mfma_f32_16x16x32_f16(kfh[ms][1], qm[qs][1], am[qs][ms], 0, 0, 0);
                am[qs][ms] = __builtin_amdgcn_mfma_f32_16x16x32_f16(kfl[ms][1], qh[qs][1], am[qs][ms], 0, 0, 0);
            }
        }
        __builtin_amdgcn_s_setprio(0);

        // softmax: p = exp2(s) -> P limb planes (cvt_pkrtz packed)
        #pragma unroll
        for (int qs = 0; qs < 2; qs++) {
            #pragma unroll
            for (int ms = 0; ms < 2; ms++) {
                float p0 = __builtin_amdgcn_exp2f(ah[qs][ms][0] + am[qs][ms][0] * 4.8828125e-4f);
                float p1 = __builtin_amdgcn_exp2f(ah[qs][ms][1] + am[qs][ms][1] * 4.8828125e-4f);
                float p2 = __builtin_amdgcn_exp2f(ah[qs][ms][2] + am[qs][ms][2] * 4.8828125e-4f);
                float p3 = __builtin_amdgcn_exp2f(ah[qs][ms][3] + am[qs][ms][3] * 4.8828125e-4f);
                lsum[qs] += (p0 + p1) + (p2 + p3);
                fp16x2 h01 = __builtin_amdgcn_cvt_pkrtz(p0, p1);
                fp16x2 h23 = __builtin_amdgcn_cvt_pkrtz(p2, p3);
                fp16x2 m01 = __builtin_amdgcn_cvt_pkrtz((p0 - (float)h01[0]) * 2048.0f,
                                                        (p1 - (float)h01[1]) * 2048.0f);
                fp16x2 m23 = __builtin_amdgcn_cvt_pkrtz((p2 - (float)h23[0]) * 2048.0f,
                                                        (p3 - (float)h23[1]) * 2048.0f);
                int poff = wave * 1152 + (qs * 16 + l15) * 36 + ms * 16 + quad * 4;
                *(uint2*)&PhL[poff] = make_uint2(pk2u(h01), pk2u(h23));
                *(uint2*)&PlL[poff] = make_uint2(pk2u(m01), pk2u(m23));
            }
        }
        WAIT_LGKM();   // P writes visible to own wave's cross-lane reads (vmcnt untouched)

        // PV MFMAs (24): V fragments already in regs (prefetched last iteration)
        __builtin_amdgcn_s_setprio(1);
        #pragma unroll
        for (int qs = 0; qs < 2; qs++) {
            f16x8 pfh = *(const f16x8*)&PhL[wave * 1152 + (qs * 16 + l15) * 36 + quad * 8];
            f16x8 pfm = *(const f16x8*)&PlL[wave * 1152 + (qs * 16 + l15) * 36 + quad * 8];
            #pragma unroll
            for (int nh = 0; nh < 4; nh++) {
                och[qs][nh] = __builtin_amdgcn_mfma_f32_16x16x32_f16(pfh, vfh[nh], och[qs][nh], 0, 0, 0);
                ocm[qs][nh] = __builtin_amdgcn_mfma_f32_16x16x32_f16(pfh, vfm[nh], ocm[qs][nh], 0, 0, 0);
                ocm[qs][nh] = __builtin_amdgcn_mfma_f32_16x16x32_f16(pfm, vfh[nh], ocm[qs][nh], 0, 0, 0);
            }
        }
        __builtin_amdgcn_s_setprio(0);

        // prefetch V(t+1) fragments from fragment-tiled global (1KB contiguous/instr);
        // consumed at PV(t+1): slack = barrier + K stage + QK + softmax (>>L2 latency)
        if (t + 1 < 32) {
            #pragma unroll
            for (int nh = 0; nh < 4; nh++) {
                size_t vo = ((size_t)((whalf * 32 + t + 1) * 64 + nh * 16 + l15) << 5) + quad * 8;
                vfh[nh] = *(const f16x8*)(vhb + vo);
                vfm[nh] = *(const f16x8*)(vlb + vo);
            }
        }
    }

    // ---- epilogue: merge halves (plain adds — no max tracking), normalize, write ----
    Lpf[((wave * 2 + 0) * 16 + l15) * 4 + quad] = lsum[0];
    Lpf[((wave * 2 + 1) * 16 + l15) * 4 + quad] = lsum[1];
    __syncthreads();   // all PV/P-reads done + Lp visible (Om overlays P buffers)

    if (whalf == 1) {  // half1 deposits partial O into merge buffer
        #pragma unroll
        for (int qs = 0; qs < 2; qs++)
            #pragma unroll
            for (int nh = 0; nh < 4; nh++)
                #pragma unroll
                for (int r = 0; r < 4; r++)
                    Om[((((wsub * 2 + qs) * 4 + nh) * 4 + r) << 6) + lane] =
                        och[qs][nh][r] + ocm[qs][nh][r] * 4.8828125e-4f;
    }
    __syncthreads();

    if (whalf == 0) {
        int b = bh >> 4, h = bh & 15;
        #pragma unroll
        for (int qs = 0; qs < 2; qs++) {
            float linv[4];
            #pragma unroll
            for (int r = 0; r < 4; r++) {
                float4 a = *(const float4*)&Lpf[((wave * 2 + qs) * 16 + quad * 4 + r) * 4];
                float4 c = *(const float4*)&Lpf[(((wave + 4) * 2 + qs) * 16 + quad * 4 + r) * 4];
                linv[r] = 1.0f / (a.x + a.y + a.z + a.w + c.x + c.y + c.z + c.w);
            }
            #pragma unroll
            for (int nh = 0; nh < 4; nh++) {
                #pragma unroll
                for (int r = 0; r < 4; r++) {
                    int token = b * SEQ + qbase + qs * 16 + quad * 4 + r;
                    float val = (och[qs][nh][r] + ocm[qs][nh][r] * 4.8828125e-4f
                                 + Om[((((wsub * 2 + qs) * 4 + nh) * 4 + r) << 6) + lane]) * linv[r];
                    out[(size_t)token * DM + h * 64 + nh * 16 + l15] = val;
                }
            }
        }
    }
}

extern "C" void kernel_launch(void* const* d_in, const int* in_sizes, int n_in,
                              void* d_out, int out_size, void* d_ws, size_t ws_size,
                              hipStream_t stream) {
    const float* x       = (const float*)d_in[0];
    const float* context = (const float*)d_in[1];
    const float* Wq      = (const float*)d_in[2];
    const float* Wk      = (const float*)d_in[3];
    const float* Wv      = (const float*)d_in[4];
    const float* Wo      = (const float*)d_in[5];
    char* ws = (char*)d_ws;

    // workspace layout (~71.4 MB). Plane region at +21102592:
    //   Qh 8MB | Ql 8MB | Kh 8MB | Kl 8MB | Vh 8MB | Vl 8MB  (48 MB total)
    double* wscale   = (double*)(ws + 0);            // 4 doubles
    double* partial  = (double*)(ws + 4096);         // 256 doubles
    double* ascale_x = (double*)(ws + 8192);         // 8192 doubles (x then ctx)
    double* ascale_a = (double*)(ws + 73728);        // 4096 doubles
    signed char* wqb = (signed char*)(ws + 131072);          // 4 x 1 MB int8
    signed char* xq  = (signed char*)(ws + 4325376);         // 4 MB (cq follows)
    signed char* cq  = (signed char*)(ws + 8519680);         // 4 MB
    float* attn_out  = (float*)(ws + 4325376);               // aliases xq+cq region (16 MB)
    char* planes     = ws + 21102592;                        // 48 MB limb planes
    signed char* aq  = (signed char*)(ws + 21102592);        // aliases Q planes, used after attention

    unsigned short* qhg = (unsigned short*)planes;
    unsigned short* qlg = qhg + 4194304;
    unsigned short* khg = (unsigned short*)(planes + 16777216);
    unsigned short* klg = khg + 4194304;
    unsigned short* vhg = (unsigned short*)(planes + 33554432);
    unsigned short* vlg = vhg + 4194304;

    wsum1<<<dim3(64, 4), 256, 0, stream>>>(Wq, Wk, Wv, Wo, partial);
    wsum2<<<1, 64, 0, stream>>>(partial, wscale);
    wquant<<<dim3(1024, 4), 256, 0, stream>>>(Wq, Wk, Wv, Wo, wscale, wqb);
    aquant2<<<2 * NTOK, 256, 0, stream>>>(x, context, xq, ascale_x);

    gemm_qkv<<<dim3(24, 32), 256, 0, stream>>>(xq, cq, wqb, ascale_x, wscale, planes);

    attn_mfma<<<dim3(512), 512, 0, stream>>>(qhg, qlg, khg, klg, vhg, vlg, attn_out);

    aquant<<<NTOK, 256, 0, stream>>>(attn_out, aq, ascale_a);
    gemm_o<<<dim3(8, 32), 256, 0, stream>>>(aq, wqb + 3145728, ascale_a, wscale + 3, (float*)d_out);
}

// Round 12
// 292.197 us; speedup vs baseline: 3.0793x; 1.0082x over previous
//
#include <hip/hip_runtime.h>
#include <math.h>

#define HEADS   16
#define DHEAD   64
#define SEQ     2048
#define NB      2
#define DM      1024
#define NTOK    4096           // NB*SEQ
#define WEPS    1e-5

using f16x8   = __attribute__((ext_vector_type(8))) _Float16;
using f16x4   = __attribute__((ext_vector_type(4))) _Float16;
using fp16x2  = __attribute__((ext_vector_type(2))) __fp16;   // cvt_pkrtz result type
using floatx4 = __attribute__((ext_vector_type(4))) float;
using i32x4   = __attribute__((ext_vector_type(4))) int;

typedef __attribute__((address_space(1))) unsigned int gu32;
typedef __attribute__((address_space(3))) unsigned int lu32;

// lgkmcnt(0)-only barrier: does NOT drain vmcnt (register prefetch survives).
// Safe because LDS staging here is plain ds_write (not global_load_lds DMA).
#define BAR_LGKM()  asm volatile("s_waitcnt lgkmcnt(0)\n\ts_barrier" ::: "memory")
#define WAIT_LGKM() asm volatile("s_waitcnt lgkmcnt(0)" ::: "memory")

__device__ __forceinline__ unsigned short h16b(_Float16 h) {
    union { _Float16 h; unsigned short u; } c; c.h = h; return c.u;
}
__device__ __forceinline__ unsigned pk2u(fp16x2 v) {
    union { fp16x2 h; unsigned u; } c; c.h = v; return c.u;
}

// ---------------- weight |w| mean: pass 1 (partial sums in double) ----------------
__global__ void wsum1(const float* __restrict__ w0, const float* __restrict__ w1,
                      const float* __restrict__ w2, const float* __restrict__ w3,
                      double* __restrict__ partial) {
    const float* w = (blockIdx.y == 0) ? w0 : (blockIdx.y == 1) ? w1 : (blockIdx.y == 2) ? w2 : w3;
    int base = blockIdx.x * 16384;
    double s = 0.0;
    for (int i = threadIdx.x; i < 16384; i += 256)
        s += fabs((double)w[base + i]);
    __shared__ double sd[256];
    sd[threadIdx.x] = s;
    __syncthreads();
    for (int st = 128; st > 0; st >>= 1) {
        if (threadIdx.x < st) sd[threadIdx.x] += sd[threadIdx.x + st];
        __syncthreads();
    }
    if (threadIdx.x == 0) partial[blockIdx.y * 64 + blockIdx.x] = sd[0];
}

// ---------------- weight mean: pass 2 -> wscale[w] = clip(mean|w|, eps) ----------------
__global__ void wsum2(const double* __restrict__ partial, double* __restrict__ wscale) {
    int t = threadIdx.x;
    if (t < 4) {
        double s = 0.0;
        for (int i = 0; i < 64; i++) s += partial[t * 64 + i];
        double mean = s / (1024.0 * 1024.0);
        wscale[t] = (mean > WEPS) ? mean : WEPS;
    }
}

// ---------------- ternary weight quant -> int8 {-1,0,1} ----------------
__global__ void wquant(const float* __restrict__ w0, const float* __restrict__ w1,
                       const float* __restrict__ w2, const float* __restrict__ w3,
                       const double* __restrict__ wscale, signed char* __restrict__ wq) {
    int widx = blockIdx.y;
    const float* w = (widx == 0) ? w0 : (widx == 1) ? w1 : (widx == 2) ? w2 : w3;
    double ws = 1.0 / wscale[widx];
    int idx = (blockIdx.x * 256 + threadIdx.x) * 4;
    float4 wv = *(const float4*)(w + idx);
    char4 o;
    {
        double r = rint((double)wv.x * ws); r = r > 1.0 ? 1.0 : (r < -1.0 ? -1.0 : r); o.x = (signed char)r;
    } {
        double r = rint((double)wv.y * ws); r = r > 1.0 ? 1.0 : (r < -1.0 ? -1.0 : r); o.y = (signed char)r;
    } {
        double r = rint((double)wv.z * ws); r = r > 1.0 ? 1.0 : (r < -1.0 ? -1.0 : r); o.z = (signed char)r;
    } {
        double r = rint((double)wv.w * ws); r = r > 1.0 ? 1.0 : (r < -1.0 ? -1.0 : r); o.w = (signed char)r;
    }
    *(char4*)(wq + (size_t)widx * 1048576 + idx) = o;
}

// ---------------- per-token int8 absmax activation quant -> int8 ----------------
__device__ __forceinline__ void aquant_row(const float* __restrict__ row,
                                           signed char* __restrict__ dst_row,
                                           double* __restrict__ ascale_p) {
    int t = threadIdx.x;
    float4 xv = *(const float4*)(row + t * 4);
    float a = fmaxf(fmaxf(fabsf(xv.x), fabsf(xv.y)), fmaxf(fabsf(xv.z), fabsf(xv.w)));
    __shared__ float sm[256];
    sm[t] = a;
    __syncthreads();
    for (int st = 128; st > 0; st >>= 1) {
        if (t < st) sm[t] = fmaxf(sm[t], sm[t + st]);
        __syncthreads();
    }
    double mx = (double)sm[0];
    if (mx < WEPS) mx = WEPS;
    if (t == 0) *ascale_p = mx / 127.0;
    double xs = 127.0 / mx;
    char4 o;
    {
        double r = rint((double)xv.x * xs); r = r > 127.0 ? 127.0 : (r < -128.0 ? -128.0 : r); o.x = (signed char)r;
    } {
        double r = rint((double)xv.y * xs); r = r > 127.0 ? 127.0 : (r < -128.0 ? -128.0 : r); o.y = (signed char)r;
    } {
        double r = rint((double)xv.z * xs); r = r > 127.0 ? 127.0 : (r < -128.0 ? -128.0 : r); o.z = (signed char)r;
    } {
        double r = rint((double)xv.w * xs); r = r > 127.0 ? 127.0 : (r < -128.0 ? -128.0 : r); o.w = (signed char)r;
    }
    *(char4*)(dst_row + t * 4) = o;
}

__global__ void aquant(const float* __restrict__ src, signed char* __restrict__ dst,
                       double* __restrict__ ascale) {
    int tok = blockIdx.x;
    aquant_row(src + (size_t)tok * DM, dst + (size_t)tok * DM, ascale + tok);
}

// fused x + context quant: xq/cq and ascale_x/ascale_c are contiguous in ws
__global__ void aquant2(const float* __restrict__ x, const float* __restrict__ ctx,
                        signed char* __restrict__ dst, double* __restrict__ ascale) {
    int tok = blockIdx.x;
    const float* row = (tok < NTOK) ? x + (size_t)tok * DM : ctx + (size_t)(tok - NTOK) * DM;
    aquant_row(row, dst + (size_t)tok * DM, ascale + tok);
}

// ---------------- int8 MFMA GEMM core: C[m][n] = sum_k A[m][k]*W[n][k], exact i32 ----------
// m97 structure: async global_load_lds width-16 staging, 128x128 tile, BK=64.
// mode 0 (Q,K): separate hi/lo f16 limb planes at [b][h][t][dh] (lo at +4194304 elems)
// mode 2 (V):   separate limb planes, transposed+FRAGMENT-TILED [b][h][t/32][dh][t%32]
//               -> attn V-fragment f16x8 load is 1KB contiguous; ushort4 stores over t%32
// mode 1: plain fp32 [t][o].
__device__ __forceinline__ void gemm_core(
        const signed char* __restrict__ A, const signed char* __restrict__ W,
        const double* __restrict__ ascale, double wsc,
        void* __restrict__ outp, int mode, float prescale, int bx, int by) {
    __shared__ __align__(16) signed char lds_a[128 * 64];
    __shared__ __align__(16) signed char lds_b[128 * 64];
    const int tid  = threadIdx.x;
    const int wave = tid >> 6, lane = tid & 63;
    const int wr = wave >> 1, wc = wave & 1;
    const int quad = lane >> 4, l15 = lane & 15;
    const int row0 = by * 128, col0 = bx * 128;
    i32x4 acc[4][4] = {};

    const signed char* ga0 = A + (size_t)(row0 + (lane >> 2)) * DM + (lane & 3) * 16;
    const signed char* gb0 = W + (size_t)(col0 + (lane >> 2)) * DM + (lane & 3) * 16;

    for (int k0 = 0; k0 < DM; k0 += 64) {
        __syncthreads();
        #pragma unroll
        for (int t = 0; t < 2; t++) {
            const int i = wave + t * 4;                 // wave-uniform instr index, 8 total
            __builtin_amdgcn_global_load_lds(
                (const gu32*)(const void*)(ga0 + (size_t)i * 16 * DM + k0),
                (lu32*)(void*)(lds_a + i * 1024), 16, 0, 0);
            __builtin_amdgcn_global_load_lds(
                (const gu32*)(const void*)(gb0 + (size_t)i * 16 * DM + k0),
                (lu32*)(void*)(lds_b + i * 1024), 16, 0, 0);
        }
        __syncthreads();
        i32x4 af[4], bfr[4];
        #pragma unroll
        for (int mi = 0; mi < 4; mi++) {
            int r = wr * 64 + mi * 16 + l15;
            af[mi] = *(const i32x4*)&lds_a[r * 64 + quad * 16];
        }
        #pragma unroll
        for (int ni = 0; ni < 4; ni++) {
            int n = wc * 64 + ni * 16 + l15;
            bfr[ni] = *(const i32x4*)&lds_b[n * 64 + quad * 16];
        }
        #pragma unroll
        for (int mi = 0; mi < 4; mi++)
            #pragma unroll
            for (int ni = 0; ni < 4; ni++)
                acc[mi][ni] = __builtin_amdgcn_mfma_i32_16x16x64_i8(af[mi], bfr[ni], acc[mi][ni], 0, 0, 0);
    }

    #pragma unroll
    for (int mi = 0; mi < 4; mi++) {
        int tbase = row0 + wr * 64 + mi * 16 + quad * 4;
        if (mode == 2) {
            int bb = tbase >> 11, n = tbase & 2047;
            int tile = n >> 5, tin = n & 31;
            #pragma unroll
            for (int ni = 0; ni < 4; ni++) {
                int o = col0 + wc * 64 + ni * 16 + l15;
                int hh = o >> 6, dh = o & 63;
                ushort4 hv, lv;
                #pragma unroll
                for (int reg = 0; reg < 4; reg++) {
                    double sa = ascale[tbase + reg] * wsc;
                    float fv = (float)((double)acc[mi][ni][reg] * sa) * prescale;
                    _Float16 hl = (_Float16)fv;
                    _Float16 ml = (_Float16)((fv - (float)hl) * 2048.0f);
                    ((unsigned short*)&hv)[reg] = h16b(hl);
                    ((unsigned short*)&lv)[reg] = h16b(ml);
                }
                size_t idx = (((size_t)(bb * HEADS + hh) * 64 + tile) * 64 + dh) * 32 + tin;
                *(ushort4*)((unsigned short*)outp + idx)           = hv;
                *(ushort4*)((unsigned short*)outp + idx + 4194304) = lv;
            }
        } else {
            #pragma unroll
            for (int reg = 0; reg < 4; reg++) {
                int t = tbase + reg;
                double sa = ascale[t] * wsc;
                #pragma unroll
                for (int ni = 0; ni < 4; ni++) {
                    int o = col0 + wc * 64 + ni * 16 + l15;
                    float val = (float)((double)acc[mi][ni][reg] * sa);
                    if (mode == 1) {
                        ((float*)outp)[(size_t)t * DM + o] = val;
                    } else {
                        int bb = t >> 11, n = t & 2047, hh = o >> 6, dh = o & 63;
                        float fv = val * prescale;
                        _Float16 hl = (_Float16)fv;
                        _Float16 ml = (_Float16)((fv - (float)hl) * 2048.0f);
                        size_t idx = (((size_t)(bb * HEADS + hh) * SEQ + n) << 6) + dh;
                        ((unsigned short*)outp)[idx]           = h16b(hl);
                        ((unsigned short*)outp)[idx + 4194304] = h16b(ml);
                    }
                }
            }
        }
    }
}

// fused Q/K/V projections: 768 blocks = 3/CU co-resident (hides barrier drain)
// Q prescale folds softmax scale AND log2(e): 0.125 * 1.4426950408889634
__global__ __launch_bounds__(256) void gemm_qkv(
        const signed char* __restrict__ xq, const signed char* __restrict__ cq,
        const signed char* __restrict__ wqb, const double* __restrict__ ascale_x,
        const double* __restrict__ wscale, void* __restrict__ qkv) {
    const int which = blockIdx.x >> 3;          // 0=Q, 1=K, 2=V
    char* base = (char*)qkv + (size_t)which * 16777216;
    gemm_core(which == 0 ? xq : cq,
              wqb + (size_t)which * 1048576,
              ascale_x + (which ? NTOK : 0),
              wscale[which],
              base,
              which == 2 ? 2 : 0,
              which == 0 ? 0.18033688011112042f : 1.0f, blockIdx.x & 7, blockIdx.y);
}

__global__ __launch_bounds__(256) void gemm_o(
        const signed char* __restrict__ aq, const signed char* __restrict__ wo,
        const double* __restrict__ ascale, const double* __restrict__ wscale_p,
        float* __restrict__ out) {
    gemm_core(aq, wo, ascale, *wscale_p, out, 1, 1.0f, blockIdx.x, blockIdx.y);
}

// ---------------- MFMA flash attention v14: in-block KV split, 4-wave gangs ---------------
// v12/v13 post-mortem: 8-wave blocks never delivered TLP (v13: occupancy 22%, 145us — 8-wave
// barrier gangs / co-residency failure). v14 keeps v11's per-wave schedule EXACTLY and does
// the KV split with 256-thread blocks: waves 0-1 = kv-half 0, waves 2-3 = kv-half 1, same
// 64 q-rows; grid 1024 = 4 blocks/CU (LDS 36.9KB x4 = 147KB <= 160; VGPR ~124 <= 128 under
// (256,2)). Partials merge by plain addition (no running max) through an LDS overlay;
// partner wave = wave+2. K staging cooperative: each thread stages 1 (row,chunk) slot for
// BOTH halves (4 prefetched uint4). V frags in regs from fragment-tiled global, 1 tile ahead.
#define KH_IDX(row, d8) (((row) * 8 + ((d8) ^ ((row) & 7))) * 8)       // halves

__global__ __launch_bounds__(256, 2) void attn_mfma(
        const unsigned short* __restrict__ qhg, const unsigned short* __restrict__ qlg,
        const unsigned short* __restrict__ khg, const unsigned short* __restrict__ klg,
        const unsigned short* __restrict__ vhg, const unsigned short* __restrict__ vlg,
        float* __restrict__ out) {
    // smem (36864 B): KhL[2][2048]h | KlL[2][2048]h | PhL[4][1152]h | PlL[4][1152]h |
    //                 Lpf[4][2][16][4]f ; merge overlay Om (16KB f32) on PhL/PlL
    __shared__ __align__(16) char smem[36864];
    _Float16* KhL = (_Float16*)smem;                     // +0     (8 KB: 2 halves x 4KB)
    _Float16* KlL = (_Float16*)(smem + 8192);            // +8192  (8 KB)
    _Float16* PhL = (_Float16*)(smem + 16384);           // +16384 (9216 B, per wave 1152h)
    _Float16* PlL = (_Float16*)(smem + 25600);           // +25600 (9216 B)
    float*    Lpf = (float*)(smem + 34816);              // +34816 (2 KB)
    float*    Om  = (float*)(smem + 16384);              // merge overlay (16 KB <= 18 KB)

    const int lin  = blockIdx.x;
    const int bh   = (lin & 7) * 4 + ((lin >> 3) & 3);   // co-resident blocks share bh
    const int qblk = lin >> 5;                           // [0,32), 64 q-rows each
    const int tid  = threadIdx.x;
    const int wave = tid >> 6, lane = tid & 63;
    const int whalf = wave >> 1, wsub = wave & 1;        // kv-half, q-sub-block
    const int l15  = lane & 15, quad = lane >> 4;
    const int qbase = qblk * 64 + wsub * 32;

    // ---- Q fragments: direct f16x8 loads from separate limb planes ----
    f16x8 qh[2][2], qm[2][2];
    #pragma unroll
    for (int qs = 0; qs < 2; qs++) {
        #pragma unroll
        for (int c = 0; c < 2; c++) {
            size_t off = (((size_t)bh * SEQ + qbase + qs * 16 + l15) << 6) + c * 32 + quad * 8;
            qh[qs][c] = *(const f16x8*)(qhg + off);
            qm[qs][c] = *(const f16x8*)(qlg + off);
        }
    }

    floatx4 och[2][4] = {};   // [qs][nh] hi-scale PV acc
    floatx4 ocm[2][4] = {};   // [qs][nh] 2^-11-scale PV acc
    float lsum[2] = {0.f, 0.f};
    const floatx4 zf = {};    // shared zero quad for QK acc init

    const unsigned short* khb = khg + ((size_t)bh * SEQ << 6);   // [t][dh] plane
    const unsigned short* klb = klg + ((size_t)bh * SEQ << 6);
    const unsigned short* vhb = vhg + ((size_t)bh << 17);        // fragment-tiled plane
    const unsigned short* vlb = vlg + ((size_t)bh << 17);

    // cooperative K staging: thread (sk,d8) stages row sk of BOTH halves' current tile
    const int sk = tid >> 3, d8 = tid & 7;
    _Float16* KhH = KhL + whalf * 2048;                  // this wave's read buffer
    _Float16* KlH = KlL + whalf * 2048;

    // prologue: prefetch K tile 0 (both halves); V tile 0 fragments (own half)
    uint4 kh_pf0 = *(const uint4*)(khb + ((size_t)sk << 6) + d8 * 8);
    uint4 kl_pf0 = *(const uint4*)(klb + ((size_t)sk << 6) + d8 * 8);
    uint4 kh_pf1 = *(const uint4*)(khb + ((size_t)(1024 + sk) << 6) + d8 * 8);
    uint4 kl_pf1 = *(const uint4*)(klb + ((size_t)(1024 + sk) << 6) + d8 * 8);
    f16x8 vfh[4], vfm[4];
    #pragma unroll
    for (int nh = 0; nh < 4; nh++) {
        size_t vo = ((size_t)((whalf * 32) * 64 + nh * 16 + l15) << 5) + quad * 8;
        vfh[nh] = *(const f16x8*)(vhb + vo);
        vfm[nh] = *(const f16x8*)(vlb + vo);
    }

    for (int t = 0; t < 32; t++) {
        BAR_LGKM();   // LDS reads from previous tile done (no vmcnt drain)

        *(uint4*)&KhL[KH_IDX(sk, d8)]        = kh_pf0;   // half 0 stage
        *(uint4*)&KlL[KH_IDX(sk, d8)]        = kl_pf0;
        *(uint4*)&KhL[2048 + KH_IDX(sk, d8)] = kh_pf1;   // half 1 stage
        *(uint4*)&KlL[2048 + KH_IDX(sk, d8)] = kl_pf1;

        if (t + 1 < 32) {   // prefetch K(t+1), both halves: full tile of latency tolerance
            kh_pf0 = *(const uint4*)(khb + ((size_t)((t + 1) * 32 + sk) << 6) + d8 * 8);
            kl_pf0 = *(const uint4*)(klb + ((size_t)((t + 1) * 32 + sk) << 6) + d8 * 8);
            kh_pf1 = *(const uint4*)(khb + ((size_t)(1024 + (t + 1) * 32 + sk) << 6) + d8 * 8);
            kl_pf1 = *(const uint4*)(klb + ((size_t)(1024 + (t + 1) * 32 + sk) << 6) + d8 * 8);
        }

        BAR_LGKM();   // staged K visible

        // K fragments (A-operand), direct f16x8 from this wave's half buffer
        f16x8 kfh[2][2], kfl[2][2];
        #pragma unroll
        for (int ms = 0; ms < 2; ms++) {
            #pragma unroll
            for (int c = 0; c < 2; c++) {
                kfh[ms][c] = *(const f16x8*)&KhH[KH_IDX(ms * 16 + l15, c * 4 + quad)];
                kfl[ms][c] = *(const f16x8*)&KlH[KH_IDX(ms * 16 + l15, c * 4 + quad)];
            }
        }

        // QK MFMAs (24): 2 qs x 2 ms x 6
        __builtin_amdgcn_s_setprio(1);
        floatx4 ah[2][2], am[2][2];
        #pragma unroll
        for (int qs = 0; qs < 2; qs++) {
            #pragma unroll
            for (int ms = 0; ms < 2; ms++) {
                ah[qs][ms] = __builtin_amdgcn_mfma_f32_16x16x32_f16(kfh[ms][0], qh[qs][0], zf, 0, 0, 0);
                am[qs][ms] = __builtin_amdgcn_mfma_f32_16x16x32_f16(kfh[ms][0], qm[qs][0], zf, 0, 0, 0);
                am[qs][ms] = __builtin_amdgcn_mfma_f32_16x16x32_f16(kfl[ms][0], qh[qs][0], am[qs][ms], 0, 0, 0);
                ah[qs][ms] = __builtin_amdgcn_mfma_f32_16x16x32_f16(kfh[ms][1], qh[qs][1], ah[qs][ms], 0, 0, 0);
                am[qs][ms] = __builtin_amdgcn_mfma_f32_16x16x32_f16(kfh[ms][1], qm[qs][1], am[qs][ms], 0, 0, 0);
                am[qs][ms] = __builtin_amdgcn_mfma_f32_16x16x32_f16(kfl[ms][1], qh[qs][1], am[qs][ms], 0, 0, 0);
            }
        }
        __builtin_amdgcn_s_setprio(0);

        // softmax: p = exp2(s) -> P limb planes (cvt_pkrtz packed)
        #pragma unroll
        for (int qs = 0; qs < 2; qs++) {
            #pragma unroll
            for (int ms = 0; ms < 2; ms++) {
                float p0 = __builtin_amdgcn_exp2f(ah[qs][ms][0] + am[qs][ms][0] * 4.8828125e-4f);
                float p1 = __builtin_amdgcn_exp2f(ah[qs][ms][1] + am[qs][ms][1] * 4.8828125e-4f);
                float p2 = __builtin_amdgcn_exp2f(ah[qs][ms][2] + am[qs][ms][2] * 4.8828125e-4f);
                float p3 = __builtin_amdgcn_exp2f(ah[qs][ms][3] + am[qs][ms][3] * 4.8828125e-4f);
                lsum[qs] += (p0 + p1) + (p2 + p3);
                fp16x2 h01 = __builtin_amdgcn_cvt_pkrtz(p0, p1);
                fp16x2 h23 = __builtin_amdgcn_cvt_pkrtz(p2, p3);
                fp16x2 m01 = __builtin_amdgcn_cvt_pkrtz((p0 - (float)h01[0]) * 2048.0f,
                                                        (p1 - (float)h01[1]) * 2048.0f);
                fp16x2 m23 = __builtin_amdgcn_cvt_pkrtz((p2 - (float)h23[0]) * 2048.0f,
                                                        (p3 - (float)h23[1]) * 2048.0f);
                int poff = wave * 1152 + (qs * 16 + l15) * 36 + ms * 16 + quad * 4;
                *(uint2*)&PhL[poff] = make_uint2(pk2u(h01), pk2u(h23));
                *(uint2*)&PlL[poff] = make_uint2(pk2u(m01), pk2u(m23));
            }
        }
        WAIT_LGKM();   // P writes visible to own wave's cross-lane reads (vmcnt untouched)

        // PV MFMAs (24): V fragments already in regs (prefetched last iteration)
        __builtin_amdgcn_s_setprio(1);
        #pragma unroll
        for (int qs = 0; qs < 2; qs++) {
            f16x8 pfh = *(const f16x8*)&PhL[wave * 1152 + (qs * 16 + l15) * 36 + quad * 8];
            f16x8 pfm = *(const f16x8*)&PlL[wave * 1152 + (qs * 16 + l15) * 36 + quad * 8];
            #pragma unroll
            for (int nh = 0; nh < 4; nh++) {
                och[qs][nh] = __builtin_amdgcn_mfma_f32_16x16x32_f16(pfh, vfh[nh], och[qs][nh], 0, 0, 0);
                ocm[qs][nh] = __builtin_amdgcn_mfma_f32_16x16x32_f16(pfh, vfm[nh], ocm[qs][nh], 0, 0, 0);
                ocm[qs][nh] = __builtin_amdgcn_mfma_f32_16x16x32_f16(pfm, vfh[nh], ocm[qs][nh], 0, 0, 0);
            }
        }
        __builtin_amdgcn_s_setprio(0);

        // prefetch V(t+1) fragments from fragment-tiled global (1KB contiguous/instr);
        // consumed at PV(t+1): slack = barrier + K stage + QK + softmax (>>L2 latency)
        if (t + 1 < 32) {
            #pragma unroll
            for (int nh = 0; nh < 4; nh++) {
                size_t vo = ((size_t)((whalf * 32 + t + 1) * 64 + nh * 16 + l15) << 5) + quad * 8;
                vfh[nh] = *(const f16x8*)(vhb + vo);
                vfm[nh] = *(const f16x8*)(vlb + vo);
            }
        }
    }

    // ---- epilogue: merge halves (plain adds — no max tracking), normalize, write ----
    Lpf[((wave * 2 + 0) * 16 + l15) * 4 + quad] = lsum[0];
    Lpf[((wave * 2 + 1) * 16 + l15) * 4 + quad] = lsum[1];
    __syncthreads();   // all PV/P-reads done + Lp visible (Om overlays P buffers)

    if (whalf == 1) {  // half-1 waves deposit partial O into merge buffer
        #pragma unroll
        for (int qs = 0; qs < 2; qs++)
            #pragma unroll
            for (int nh = 0; nh < 4; nh++)
                #pragma unroll
                for (int r = 0; r < 4; r++)
                    Om[((((wsub * 2 + qs) * 4 + nh) * 4 + r) << 6) + lane] =
                        och[qs][nh][r] + ocm[qs][nh][r] * 4.8828125e-4f;
    }
    __syncthreads();

    if (whalf == 0) {  // half-0 waves merge (partner = wave+2), normalize, write
        int b = bh >> 4, h = bh & 15;
        #pragma unroll
        for (int qs = 0; qs < 2; qs++) {
            float linv[4];
            #pragma unroll
            for (int r = 0; r < 4; r++) {
                float4 a = *(const float4*)&Lpf[((wave * 2 + qs) * 16 + quad * 4 + r) * 4];
                float4 c = *(const float4*)&Lpf[(((wave + 2) * 2 + qs) * 16 + quad * 4 + r) * 4];
                linv[r] = 1.0f / (a.x + a.y + a.z + a.w + c.x + c.y + c.z + c.w);
            }
            #pragma unroll
            for (int nh = 0; nh < 4; nh++) {
                #pragma unroll
                for (int r = 0; r < 4; r++) {
                    int token = b * SEQ + qbase + qs * 16 + quad * 4 + r;
                    float val = (och[qs][nh][r] + ocm[qs][nh][r] * 4.8828125e-4f
                                 + Om[((((wsub * 2 + qs) * 4 + nh) * 4 + r) << 6) + lane]) * linv[r];
                    out[(size_t)token * DM + h * 64 + nh * 16 + l15] = val;
                }
            }
        }
    }
}

extern "C" void kernel_launch(void* const* d_in, const int* in_sizes, int n_in,
                              void* d_out, int out_size, void* d_ws, size_t ws_size,
                              hipStream_t stream) {
    const float* x       = (const float*)d_in[0];
    const float* context = (const float*)d_in[1];
    const float* Wq      = (const float*)d_in[2];
    const float* Wk      = (const float*)d_in[3];
    const float* Wv      = (const float*)d_in[4];
    const float* Wo      = (const float*)d_in[5];
    char* ws = (char*)d_ws;

    // workspace layout (~71.4 MB). Plane region at +21102592:
    //   Qh 8MB | Ql 8MB | Kh 8MB | Kl 8MB | Vh 8MB | Vl 8MB  (48 MB total)
    double* wscale   = (double*)(ws + 0);            // 4 doubles
    double* partial  = (double*)(ws + 4096);         // 256 doubles
    double* ascale_x = (double*)(ws + 8192);         // 8192 doubles (x then ctx)
    double* ascale_a = (double*)(ws + 73728);        // 4096 doubles
    signed char* wqb = (signed char*)(ws + 131072);          // 4 x 1 MB int8
    signed char* xq  = (signed char*)(ws + 4325376);         // 4 MB (cq follows)
    signed char* cq  = (signed char*)(ws + 8519680);         // 4 MB
    float* attn_out  = (float*)(ws + 4325376);               // aliases xq+cq region (16 MB)
    char* planes     = ws + 21102592;                        // 48 MB limb planes
    signed char* aq  = (signed char*)(ws + 21102592);        // aliases Q planes, used after attention

    unsigned short* qhg = (unsigned short*)planes;
    unsigned short* qlg = qhg + 4194304;
    unsigned short* khg = (unsigned short*)(planes + 16777216);
    unsigned short* klg = khg + 4194304;
    unsigned short* vhg = (unsigned short*)(planes + 33554432);
    unsigned short* vlg = vhg + 4194304;

    wsum1<<<dim3(64, 4), 256, 0, stream>>>(Wq, Wk, Wv, Wo, partial);
    wsum2<<<1, 64, 0, stream>>>(partial, wscale);
    wquant<<<dim3(1024, 4), 256, 0, stream>>>(Wq, Wk, Wv, Wo, wscale, wqb);
    aquant2<<<2 * NTOK, 256, 0, stream>>>(x, context, xq, ascale_x);

    gemm_qkv<<<dim3(24, 32), 256, 0, stream>>>(xq, cq, wqb, ascale_x, wscale, planes);

    attn_mfma<<<dim3(1024), 256, 0, stream>>>(qhg, qlg, khg, klg, vhg, vlg, attn_out);

    aquant<<<NTOK, 256, 0, stream>>>(attn_out, aq, ascale_a);
    gemm_o<<<dim3(8, 32), 256, 0, stream>>>(aq, wqb + 3145728, ascale_a, wscale + 3, (float*)d_out);
}